// Round 1
// 3782.028 us; speedup vs baseline: 1.3732x; 1.3732x over previous
//
#include <hip/hip_runtime.h>
#include <hip/hip_bf16.h>

// GridCellRouter: N=4096*4096 cells, 16 iterations of
//   accum[idx[i]] += cur[i];  cur[i] = accum[i] - cur[i]
//
// Recurrence (verified R4): c_{t+1} = S c_t + c_{t-1}, answer = c16 + c15.
//
// R8: baby-step/giant-step (Paterson-Stockmeyer) on the polynomial
//   answer = sum_{k=0..16} alpha_k S^k r,  alpha from Fibonacci binomials
//   (c_t = sum_j C(t-j,j) S^{t-2j}; sum alpha = F_18 = 2584, checked).
// Key fact: S^k is itself a one-nonzero-per-column scatter along the
// composed index, so applying T = S^4 costs the same ~1 GB of random
// cache-line traffic as applying S once. BSGS with b=4 needs only
//   3 applications of S   (B1 = S r, B2 = S B1, B3 = S B2)
// + 4 applications of T   (Horner: g = T g + w_q, w_q fused in epilogue)
// = 7 random-gather passes instead of 16.
//
// Edge machinery (b1/s1/s2/s3/b3) is the R7-verified build, parameterized
// by `set` (0: S from idx, 1: T from idx4 = idx o idx o idx o idx).
// ALL indices masked/clamped -> no OOB access possible anywhere.
// d_in[0] (runoff) is now read-only; answer lands in d_out.

#define N_CELLS (1 << 24)

#define BKT_BITS 12
#define NBKT (N_CELLS >> BKT_BITS)        // 4096 buckets
#define DPB (1 << BKT_BITS)               // 4096 dsts per bucket
#define BKT_MASK (DPB - 1)
#define IDX_MASK (N_CELLS - 1)
#define G1 256                            // wgs in b1/b3
#define EDGES_PER_WG (N_CELLS / G1)       // 65536

__device__ __align__(16) unsigned g_T[2][NBKT * G1];          // (bucket,wg) offsets
__device__ __align__(16) unsigned short g_dst16[2][N_CELLS];  // dst low 12 bits
__device__ __align__(16) unsigned g_srcid[2][N_CELLS];        // sender ids
__device__ __align__(16) unsigned g_bktcnt[2][NBKT];          // bucket totals
__device__ __align__(16) unsigned g_S[2][NBKT + 4];           // bucket starts (excl)
__device__ __align__(16) int g_idx2[N_CELLS];                 // idx o idx
__device__ __align__(16) int g_idx4[N_CELLS];                 // idx2 o idx2
__device__ __align__(16) float gB1[N_CELLS];                  // S r
__device__ __align__(16) float gB2[N_CELLS];                  // S^2 r
__device__ __align__(16) float gB3[N_CELLS];                  // S^3 r
__device__ __align__(16) float gH[N_CELLS];                   // Horner ping buffer

// compose: mode 0: g_idx2[i] = ext[ext[i]];  mode 1: g_idx4[i] = g_idx2[g_idx2[i]]
__global__ void compose_idx(const int* __restrict__ ext, int mode) {
    const int* __restrict__ a = mode ? g_idx2 : ext;
    int* __restrict__ o = mode ? g_idx4 : g_idx2;
    int i = (blockIdx.x * 256 + threadIdx.x) * 4;
    int4 v = *reinterpret_cast<const int4*>(a + i);
    int4 r;
    r.x = a[v.x & IDX_MASK];
    r.y = a[v.y & IDX_MASK];
    r.z = a[v.z & IDX_MASK];
    r.w = a[v.w & IDX_MASK];
    *reinterpret_cast<int4*>(o + i) = r;
}

// b1: count edges per (bucket, wg)
__global__ void b1_count(const int* __restrict__ ext, int set) {
    const int* __restrict__ idx = set ? g_idx4 : ext;
    __shared__ unsigned h[NBKT];
    int t = threadIdx.x;
    for (int k = t; k < NBKT; k += 256) h[k] = 0u;
    __syncthreads();
    const uint4* p = reinterpret_cast<const uint4*>(idx) + (size_t)blockIdx.x * (EDGES_PER_WG / 4);
    for (int k = 0; k < EDGES_PER_WG / 4 / 256; ++k) {   // 64 iters
        uint4 v = p[k * 256 + t];
        atomicAdd(&h[(v.x & IDX_MASK) >> BKT_BITS], 1u);
        atomicAdd(&h[(v.y & IDX_MASK) >> BKT_BITS], 1u);
        atomicAdd(&h[(v.z & IDX_MASK) >> BKT_BITS], 1u);
        atomicAdd(&h[(v.w & IDX_MASK) >> BKT_BITS], 1u);
    }
    __syncthreads();
    for (int b = t; b < NBKT; b += 256) g_T[set][(size_t)b * G1 + blockIdx.x] = h[b];
}

// s1: bucket totals (one wg per bucket, row is contiguous)
__global__ void s1_sums(int set) {
    __shared__ unsigned sd[256];
    int t = threadIdx.x;
    sd[t] = g_T[set][(size_t)blockIdx.x * G1 + t];
    __syncthreads();
    for (int off = 128; off > 0; off >>= 1) {
        if (t < off) sd[t] += sd[t + off];
        __syncthreads();
    }
    if (t == 0) g_bktcnt[set][blockIdx.x] = sd[0];
}

// s2: exclusive scan of g_bktcnt[4096] -> g_S (R3-proven pattern)
__global__ void s2_scan(int set) {
    __shared__ unsigned s[1024];
    int t = threadIdx.x;
    uint4 v = reinterpret_cast<const uint4*>(g_bktcnt[set])[t];
    unsigned local = v.x + v.y + v.z + v.w;
    s[t] = local;
    __syncthreads();
    for (int off = 1; off < 1024; off <<= 1) {
        unsigned add = (t >= off) ? s[t - off] : 0u;
        __syncthreads();
        s[t] += add;
        __syncthreads();
    }
    unsigned run = s[t] - local;   // exclusive prefix of this thread
    uint4 o;
    o.x = run; run += v.x;
    o.y = run; run += v.y;
    o.z = run; run += v.z;
    o.w = run;
    reinterpret_cast<uint4*>(g_S[set])[t] = o;
    if (t == 0) g_S[set][NBKT] = (unsigned)N_CELLS;
}

// s3: within-bucket exclusive scan of 256 wg counts + bucket base
__global__ void s3_offsets(int set) {
    __shared__ unsigned s[256];
    int t = threadIdx.x;
    unsigned v = g_T[set][(size_t)blockIdx.x * G1 + t];
    s[t] = v;
    __syncthreads();
    for (int off = 1; off < 256; off <<= 1) {
        unsigned add = (t >= off) ? s[t - off] : 0u;
        __syncthreads();
        s[t] += add;
        __syncthreads();
    }
    g_T[set][(size_t)blockIdx.x * G1 + t] = g_S[set][blockIdx.x] + s[t] - v;
}

// b3: scatter (dst12, sender id) bucket-grouped via per-wg LDS cursors
__global__ void b3_scatter(const int* __restrict__ ext, int set) {
    const int* __restrict__ idx = set ? g_idx4 : ext;
    __shared__ unsigned cur[NBKT];
    int t = threadIdx.x;
    for (int b = t; b < NBKT; b += 256) cur[b] = g_T[set][(size_t)b * G1 + blockIdx.x];
    __syncthreads();
    unsigned base = blockIdx.x * EDGES_PER_WG;
    const uint4* p = reinterpret_cast<const uint4*>(idx) + (size_t)blockIdx.x * (EDGES_PER_WG / 4);
    for (int k = 0; k < EDGES_PER_WG / 4 / 256; ++k) {
        unsigned e4 = base + (k * 256 + t) * 4;
        uint4 v = p[k * 256 + t];
        unsigned pos;
        pos = atomicAdd(&cur[(v.x & IDX_MASK) >> BKT_BITS], 1u) & IDX_MASK;
        g_dst16[set][pos] = (unsigned short)(v.x & BKT_MASK); g_srcid[set][pos] = e4;
        pos = atomicAdd(&cur[(v.y & IDX_MASK) >> BKT_BITS], 1u) & IDX_MASK;
        g_dst16[set][pos] = (unsigned short)(v.y & BKT_MASK); g_srcid[set][pos] = e4 + 1;
        pos = atomicAdd(&cur[(v.z & IDX_MASK) >> BKT_BITS], 1u) & IDX_MASK;
        g_dst16[set][pos] = (unsigned short)(v.z & BKT_MASK); g_srcid[set][pos] = e4 + 2;
        pos = atomicAdd(&cur[(v.w & IDX_MASK) >> BKT_BITS], 1u) & IDX_MASK;
        g_dst16[set][pos] = (unsigned short)(v.w & BKT_MASK); g_srcid[set][pos] = e4 + 3;
    }
}

// pointer selector (host can't take addresses of __device__ statics)
__device__ __forceinline__ float* sel_buf(int which, const float* r, float* dout) {
    switch (which) {
        case 0: return (float*)r;
        case 1: return gB1;
        case 2: return gB2;
        case 3: return gB3;
        case 4: return gH;
        default: return dout;
    }
}

// apply one scatter operator (set 0: S, set 1: T=S^4):
//   out[row] = sum_{e in bucket, dst=row} ct[srcid[e]]
//            + (fuse ? a0*r + a1*B1 + a2*B2 + a3*B3 : 0)
// One wg per bucket; acc[4096] in LDS via float atomics. All indices masked.
__global__ void __launch_bounds__(256) apply_op(const float* __restrict__ rin,
                                                float* __restrict__ dout,
                                                int ct_sel, int out_sel, int set, int fuse,
                                                float a0, float a1, float a2, float a3) {
    __shared__ float acc[DPB];
    int t = threadIdx.x;
    unsigned b = blockIdx.x;
    const float* __restrict__ ct = sel_buf(ct_sel, rin, dout);
    float* __restrict__ out = sel_buf(out_sel, rin, dout);
    unsigned base = g_S[set][b];
    unsigned end = g_S[set][b + 1];
    if (end > (unsigned)N_CELLS) end = (unsigned)N_CELLS;
    if (base > end) base = end;
    float4* acc4 = reinterpret_cast<float4*>(acc);
    float4 z = {0.f, 0.f, 0.f, 0.f};
    for (int k = 0; k < DPB / 4 / 256; ++k) acc4[k * 256 + t] = z;   // 4 iters
    __syncthreads();
    const unsigned short* __restrict__ d16 = g_dst16[set];
    const unsigned* __restrict__ sid = g_srcid[set];
    for (unsigned e = base + t; e < end; e += 256) {
        float v = ct[sid[e] & IDX_MASK];
        atomicAdd(&acc[d16[e] & BKT_MASK], v);
    }
    __syncthreads();
    size_t rowbase = ((size_t)b << (BKT_BITS - 2));
    float4* out4 = reinterpret_cast<float4*>(out) + rowbase;
    if (fuse) {
        const float4* r4 = reinterpret_cast<const float4*>(rin) + rowbase;
        const float4* b14 = reinterpret_cast<const float4*>(gB1) + rowbase;
        const float4* b24 = reinterpret_cast<const float4*>(gB2) + rowbase;
        const float4* b34 = reinterpret_cast<const float4*>(gB3) + rowbase;
        for (int k = 0; k < DPB / 4 / 256; ++k) {
            int j = k * 256 + t;
            float4 a = acc4[j];
            float4 x = r4[j], y = b14[j], u = b24[j], w = b34[j];
            a.x += a0 * x.x + a1 * y.x + a2 * u.x + a3 * w.x;
            a.y += a0 * x.y + a1 * y.y + a2 * u.y + a3 * w.y;
            a.z += a0 * x.z + a1 * y.z + a2 * u.z + a3 * w.z;
            a.w += a0 * x.w + a1 * y.w + a2 * u.w + a3 * w.w;
            out4[j] = a;
        }
    } else {
        for (int k = 0; k < DPB / 4 / 256; ++k) out4[k * 256 + t] = acc4[k * 256 + t];
    }
}

extern "C" void kernel_launch(void* const* d_in, const int* in_sizes, int n_in,
                              void* d_out, int out_size, void* d_ws, size_t ws_size,
                              hipStream_t stream) {
    const int* idx = (const int*)d_in[1];
    const float* r = (const float*)d_in[0];   // read-only now
    float* out = (float*)d_out;

    // ---- build S edges (set 0) ----
    b1_count<<<G1, 256, 0, stream>>>(idx, 0);
    s1_sums<<<NBKT, 256, 0, stream>>>(0);
    s2_scan<<<1, 1024, 0, stream>>>(0);
    s3_offsets<<<NBKT, 256, 0, stream>>>(0);
    b3_scatter<<<G1, 256, 0, stream>>>(idx, 0);

    // ---- idx4 = idx o idx o idx o idx; build T edges (set 1) ----
    compose_idx<<<N_CELLS / 4 / 256, 256, 0, stream>>>(idx, 0);  // g_idx2
    compose_idx<<<N_CELLS / 4 / 256, 256, 0, stream>>>(idx, 1);  // g_idx4
    b1_count<<<G1, 256, 0, stream>>>(idx, 1);
    s1_sums<<<NBKT, 256, 0, stream>>>(1);
    s2_scan<<<1, 1024, 0, stream>>>(1);
    s3_offsets<<<NBKT, 256, 0, stream>>>(1);
    b3_scatter<<<G1, 256, 0, stream>>>(idx, 1);

    // ---- baby steps: B1 = S r, B2 = S B1, B3 = S B2 ----
    apply_op<<<NBKT, 256, 0, stream>>>(r, out, 0, 1, 0, 0, 0.f, 0.f, 0.f, 0.f);
    apply_op<<<NBKT, 256, 0, stream>>>(r, out, 1, 2, 0, 0, 0.f, 0.f, 0.f, 0.f);
    apply_op<<<NBKT, 256, 0, stream>>>(r, out, 2, 3, 0, 0, 0.f, 0.f, 0.f, 0.f);

    // ---- giant steps: Horner over T = S^4 ----
    // answer = sum_q T^q w_q, w_q = a_{4q} r + a_{4q+1} B1 + a_{4q+2} B2 + a_{4q+3} B3
    // alpha (k=0..16): 1,8,36,84,210,252,462,330,495,220,286,78,91,14,15,1,1
    // g4 = w4 = r
    // g3 = T g4 + w3 : (91,14,15,1)      -> gH
    apply_op<<<NBKT, 256, 0, stream>>>(r, out, 0, 4, 1, 1, 91.f, 14.f, 15.f, 1.f);
    // g2 = T g3 + w2 : (495,220,286,78)  -> d_out
    apply_op<<<NBKT, 256, 0, stream>>>(r, out, 4, 5, 1, 1, 495.f, 220.f, 286.f, 78.f);
    // g1 = T g2 + w1 : (210,252,462,330) -> gH
    apply_op<<<NBKT, 256, 0, stream>>>(r, out, 5, 4, 1, 1, 210.f, 252.f, 462.f, 330.f);
    // g0 = T g1 + w0 : (1,8,36,84)       -> d_out  (= answer)
    apply_op<<<NBKT, 256, 0, stream>>>(r, out, 4, 5, 1, 1, 1.f, 8.f, 36.f, 84.f);
}

// Round 3
// 3539.898 us; speedup vs baseline: 1.4671x; 1.0684x over previous
//
#include <hip/hip_runtime.h>
#include <hip/hip_bf16.h>

// GridCellRouter: N=4096*4096 cells, 16 iterations of
//   accum[idx[i]] += cur[i];  cur[i] = accum[i] - cur[i]
//
// Recurrence (verified R4): c_{t+1} = S c_t + c_{t-1}, answer = c16 + c15.
//
// R8 (verified): baby-step/giant-step on answer = sum_{k=0..16} alpha_k S^k r,
//   alpha = [1,8,36,84,210,252,462,330,495,220,286,78,91,14,15,1,1] (sum F_18).
//   3 applies of S (B1,B2,B3) + 4 applies of T=S^4 (Horner, w_q fused) = 7
//   random-gather passes instead of 16.
//
// R9 = R8 + three micro-structural fixes driven by counters:
//   * b1/b3 were 1 wg/CU (10.4% occupancy) -> 1024-thread wgs (16 waves/CU)
//   * edge record packed into one uint2 (srcid, dst12) -> ONE scattered store
//     per edge in b3 (was two, into two arrays); one coalesced load in apply
//   * apply gather loop unrolled x4 -> 4 independent random gathers in flight
// ALL indices masked/clamped -> no OOB access possible anywhere.
// (R10 resubmit: R9 never ran — GPU broker timeout, no counters.)

#define N_CELLS (1 << 24)

#define BKT_BITS 12
#define NBKT (N_CELLS >> BKT_BITS)        // 4096 buckets
#define DPB (1 << BKT_BITS)               // 4096 dsts per bucket
#define BKT_MASK (DPB - 1)
#define IDX_MASK (N_CELLS - 1)
#define G1 256                            // wgs in b1/b3
#define EDGES_PER_WG (N_CELLS / G1)       // 65536
#define BT 1024                           // threads in b1/b3

__device__ __align__(16) unsigned g_T[2][NBKT * G1];       // (bucket,wg) offsets
__device__ __align__(16) uint2 g_edge[2][N_CELLS];         // packed (srcid, dst12)
__device__ __align__(16) unsigned g_bktcnt[2][NBKT];       // bucket totals
__device__ __align__(16) unsigned g_S[2][NBKT + 4];        // bucket starts (excl)
__device__ __align__(16) int g_idx2[N_CELLS];              // idx o idx
__device__ __align__(16) int g_idx4[N_CELLS];              // idx2 o idx2
__device__ __align__(16) float gB1[N_CELLS];               // S r
__device__ __align__(16) float gB2[N_CELLS];               // S^2 r
__device__ __align__(16) float gB3[N_CELLS];               // S^3 r
__device__ __align__(16) float gH[N_CELLS];                // Horner ping buffer

// compose: mode 0: g_idx2[i] = ext[ext[i]];  mode 1: g_idx4[i] = g_idx2[g_idx2[i]]
__global__ void compose_idx(const int* __restrict__ ext, int mode) {
    const int* __restrict__ a = mode ? g_idx2 : ext;
    int* __restrict__ o = mode ? g_idx4 : g_idx2;
    int i = (blockIdx.x * 256 + threadIdx.x) * 4;
    int4 v = *reinterpret_cast<const int4*>(a + i);
    int4 r;
    r.x = a[v.x & IDX_MASK];
    r.y = a[v.y & IDX_MASK];
    r.z = a[v.z & IDX_MASK];
    r.w = a[v.w & IDX_MASK];
    *reinterpret_cast<int4*>(o + i) = r;
}

// b1: count edges per (bucket, wg).  1024 threads -> 16 waves/CU.
__global__ void __launch_bounds__(BT) b1_count(const int* __restrict__ ext, int set) {
    const int* __restrict__ idx = set ? g_idx4 : ext;
    __shared__ unsigned h[NBKT];
    int t = threadIdx.x;
    for (int k = t; k < NBKT; k += BT) h[k] = 0u;
    __syncthreads();
    const uint4* p = reinterpret_cast<const uint4*>(idx) + (size_t)blockIdx.x * (EDGES_PER_WG / 4);
    for (int k = 0; k < EDGES_PER_WG / 4 / BT; ++k) {   // 16 iters
        uint4 v = p[k * BT + t];
        atomicAdd(&h[(v.x & IDX_MASK) >> BKT_BITS], 1u);
        atomicAdd(&h[(v.y & IDX_MASK) >> BKT_BITS], 1u);
        atomicAdd(&h[(v.z & IDX_MASK) >> BKT_BITS], 1u);
        atomicAdd(&h[(v.w & IDX_MASK) >> BKT_BITS], 1u);
    }
    __syncthreads();
    for (int b = t; b < NBKT; b += BT) g_T[set][(size_t)b * G1 + blockIdx.x] = h[b];
}

// s1: bucket totals (one wg per bucket, row is contiguous)
__global__ void s1_sums(int set) {
    __shared__ unsigned sd[256];
    int t = threadIdx.x;
    sd[t] = g_T[set][(size_t)blockIdx.x * G1 + t];
    __syncthreads();
    for (int off = 128; off > 0; off >>= 1) {
        if (t < off) sd[t] += sd[t + off];
        __syncthreads();
    }
    if (t == 0) g_bktcnt[set][blockIdx.x] = sd[0];
}

// s2: exclusive scan of g_bktcnt[4096] -> g_S (R3-proven pattern)
__global__ void s2_scan(int set) {
    __shared__ unsigned s[1024];
    int t = threadIdx.x;
    uint4 v = reinterpret_cast<const uint4*>(g_bktcnt[set])[t];
    unsigned local = v.x + v.y + v.z + v.w;
    s[t] = local;
    __syncthreads();
    for (int off = 1; off < 1024; off <<= 1) {
        unsigned add = (t >= off) ? s[t - off] : 0u;
        __syncthreads();
        s[t] += add;
        __syncthreads();
    }
    unsigned run = s[t] - local;   // exclusive prefix of this thread
    uint4 o;
    o.x = run; run += v.x;
    o.y = run; run += v.y;
    o.z = run; run += v.z;
    o.w = run;
    reinterpret_cast<uint4*>(g_S[set])[t] = o;
    if (t == 0) g_S[set][NBKT] = (unsigned)N_CELLS;
}

// s3: within-bucket exclusive scan of 256 wg counts + bucket base
__global__ void s3_offsets(int set) {
    __shared__ unsigned s[256];
    int t = threadIdx.x;
    unsigned v = g_T[set][(size_t)blockIdx.x * G1 + t];
    s[t] = v;
    __syncthreads();
    for (int off = 1; off < 256; off <<= 1) {
        unsigned add = (t >= off) ? s[t - off] : 0u;
        __syncthreads();
        s[t] += add;
        __syncthreads();
    }
    g_T[set][(size_t)blockIdx.x * G1 + t] = g_S[set][blockIdx.x] + s[t] - v;
}

// b3: scatter packed (srcid, dst12) bucket-grouped via per-wg LDS cursors.
// 1024 threads -> 16 waves/CU; ONE 8B scattered store per edge.
__global__ void __launch_bounds__(BT) b3_scatter(const int* __restrict__ ext, int set) {
    const int* __restrict__ idx = set ? g_idx4 : ext;
    uint2* __restrict__ ed = g_edge[set];
    __shared__ unsigned cur[NBKT];
    int t = threadIdx.x;
    for (int b = t; b < NBKT; b += BT) cur[b] = g_T[set][(size_t)b * G1 + blockIdx.x];
    __syncthreads();
    unsigned base = blockIdx.x * EDGES_PER_WG;
    const uint4* p = reinterpret_cast<const uint4*>(idx) + (size_t)blockIdx.x * (EDGES_PER_WG / 4);
    for (int k = 0; k < EDGES_PER_WG / 4 / BT; ++k) {   // 16 iters
        unsigned e4 = base + (k * BT + t) * 4;
        uint4 v = p[k * BT + t];
        unsigned pos;
        pos = atomicAdd(&cur[(v.x & IDX_MASK) >> BKT_BITS], 1u) & IDX_MASK;
        ed[pos] = make_uint2(e4, v.x & BKT_MASK);
        pos = atomicAdd(&cur[(v.y & IDX_MASK) >> BKT_BITS], 1u) & IDX_MASK;
        ed[pos] = make_uint2(e4 + 1, v.y & BKT_MASK);
        pos = atomicAdd(&cur[(v.z & IDX_MASK) >> BKT_BITS], 1u) & IDX_MASK;
        ed[pos] = make_uint2(e4 + 2, v.z & BKT_MASK);
        pos = atomicAdd(&cur[(v.w & IDX_MASK) >> BKT_BITS], 1u) & IDX_MASK;
        ed[pos] = make_uint2(e4 + 3, v.w & BKT_MASK);
    }
}

// pointer selector (host can't take addresses of __device__ statics)
__device__ __forceinline__ float* sel_buf(int which, const float* r, float* dout) {
    switch (which) {
        case 0: return (float*)r;
        case 1: return gB1;
        case 2: return gB2;
        case 3: return gB3;
        case 4: return gH;
        default: return dout;
    }
}

// apply one scatter operator (set 0: S, set 1: T=S^4):
//   out[row] = sum_{e in bucket, dst=row} ct[srcid[e]]
//            + (fuse ? a0*r + a1*B1 + a2*B2 + a3*B3 : 0)
// One wg per bucket; acc[4096] in LDS via float atomics. All indices masked.
// Edge loop unrolled x4: 4 independent random gathers in flight per thread.
__global__ void __launch_bounds__(256) apply_op(const float* __restrict__ rin,
                                                float* __restrict__ dout,
                                                int ct_sel, int out_sel, int set, int fuse,
                                                float a0, float a1, float a2, float a3) {
    __shared__ float acc[DPB];
    int t = threadIdx.x;
    unsigned b = blockIdx.x;
    const float* __restrict__ ct = sel_buf(ct_sel, rin, dout);
    float* __restrict__ out = sel_buf(out_sel, rin, dout);
    unsigned base = g_S[set][b];
    unsigned end = g_S[set][b + 1];
    if (end > (unsigned)N_CELLS) end = (unsigned)N_CELLS;
    if (base > end) base = end;
    float4* acc4 = reinterpret_cast<float4*>(acc);
    float4 z = {0.f, 0.f, 0.f, 0.f};
    for (int k = 0; k < DPB / 4 / 256; ++k) acc4[k * 256 + t] = z;   // 4 iters
    __syncthreads();
    const uint2* __restrict__ ed = g_edge[set];
    unsigned e = base + t;
    for (; e + 768 < end; e += 1024) {
        uint2 q0 = ed[e];
        uint2 q1 = ed[e + 256];
        uint2 q2 = ed[e + 512];
        uint2 q3 = ed[e + 768];
        float v0 = ct[q0.x & IDX_MASK];
        float v1 = ct[q1.x & IDX_MASK];
        float v2 = ct[q2.x & IDX_MASK];
        float v3 = ct[q3.x & IDX_MASK];
        atomicAdd(&acc[q0.y & BKT_MASK], v0);
        atomicAdd(&acc[q1.y & BKT_MASK], v1);
        atomicAdd(&acc[q2.y & BKT_MASK], v2);
        atomicAdd(&acc[q3.y & BKT_MASK], v3);
    }
    for (; e < end; e += 256) {
        uint2 q = ed[e];
        atomicAdd(&acc[q.y & BKT_MASK], ct[q.x & IDX_MASK]);
    }
    __syncthreads();
    size_t rowbase = ((size_t)b << (BKT_BITS - 2));
    float4* out4 = reinterpret_cast<float4*>(out) + rowbase;
    if (fuse) {
        const float4* r4 = reinterpret_cast<const float4*>(rin) + rowbase;
        const float4* b14 = reinterpret_cast<const float4*>(gB1) + rowbase;
        const float4* b24 = reinterpret_cast<const float4*>(gB2) + rowbase;
        const float4* b34 = reinterpret_cast<const float4*>(gB3) + rowbase;
        for (int k = 0; k < DPB / 4 / 256; ++k) {
            int j = k * 256 + t;
            float4 a = acc4[j];
            float4 x = r4[j], y = b14[j], u = b24[j], w = b34[j];
            a.x += a0 * x.x + a1 * y.x + a2 * u.x + a3 * w.x;
            a.y += a0 * x.y + a1 * y.y + a2 * u.y + a3 * w.y;
            a.z += a0 * x.z + a1 * y.z + a2 * u.z + a3 * w.z;
            a.w += a0 * x.w + a1 * y.w + a2 * u.w + a3 * w.w;
            out4[j] = a;
        }
    } else {
        for (int k = 0; k < DPB / 4 / 256; ++k) out4[k * 256 + t] = acc4[k * 256 + t];
    }
}

extern "C" void kernel_launch(void* const* d_in, const int* in_sizes, int n_in,
                              void* d_out, int out_size, void* d_ws, size_t ws_size,
                              hipStream_t stream) {
    const int* idx = (const int*)d_in[1];
    const float* r = (const float*)d_in[0];   // read-only
    float* out = (float*)d_out;

    // ---- build S edges (set 0) ----
    b1_count<<<G1, BT, 0, stream>>>(idx, 0);
    s1_sums<<<NBKT, 256, 0, stream>>>(0);
    s2_scan<<<1, 1024, 0, stream>>>(0);
    s3_offsets<<<NBKT, 256, 0, stream>>>(0);
    b3_scatter<<<G1, BT, 0, stream>>>(idx, 0);

    // ---- idx4 = idx o idx o idx o idx; build T edges (set 1) ----
    compose_idx<<<N_CELLS / 4 / 256, 256, 0, stream>>>(idx, 0);  // g_idx2
    compose_idx<<<N_CELLS / 4 / 256, 256, 0, stream>>>(idx, 1);  // g_idx4
    b1_count<<<G1, BT, 0, stream>>>(idx, 1);
    s1_sums<<<NBKT, 256, 0, stream>>>(1);
    s2_scan<<<1, 1024, 0, stream>>>(1);
    s3_offsets<<<NBKT, 256, 0, stream>>>(1);
    b3_scatter<<<G1, BT, 0, stream>>>(idx, 1);

    // ---- baby steps: B1 = S r, B2 = S B1, B3 = S B2 ----
    apply_op<<<NBKT, 256, 0, stream>>>(r, out, 0, 1, 0, 0, 0.f, 0.f, 0.f, 0.f);
    apply_op<<<NBKT, 256, 0, stream>>>(r, out, 1, 2, 0, 0, 0.f, 0.f, 0.f, 0.f);
    apply_op<<<NBKT, 256, 0, stream>>>(r, out, 2, 3, 0, 0, 0.f, 0.f, 0.f, 0.f);

    // ---- giant steps: Horner over T = S^4 ----
    // answer = sum_q T^q w_q, w_q = a_{4q} r + a_{4q+1} B1 + a_{4q+2} B2 + a_{4q+3} B3
    // alpha (k=0..16): 1,8,36,84,210,252,462,330,495,220,286,78,91,14,15,1,1
    // g3 = T r  + w3 : (91,14,15,1)      -> gH
    apply_op<<<NBKT, 256, 0, stream>>>(r, out, 0, 4, 1, 1, 91.f, 14.f, 15.f, 1.f);
    // g2 = T g3 + w2 : (495,220,286,78)  -> d_out
    apply_op<<<NBKT, 256, 0, stream>>>(r, out, 4, 5, 1, 1, 495.f, 220.f, 286.f, 78.f);
    // g1 = T g2 + w1 : (210,252,462,330) -> gH
    apply_op<<<NBKT, 256, 0, stream>>>(r, out, 5, 4, 1, 1, 210.f, 252.f, 462.f, 330.f);
    // g0 = T g1 + w0 : (1,8,36,84)       -> d_out  (= answer)
    apply_op<<<NBKT, 256, 0, stream>>>(r, out, 4, 5, 1, 1, 1.f, 8.f, 36.f, 84.f);
}

// Round 8
// 3133.370 us; speedup vs baseline: 1.6574x; 1.1297x over previous
//
#include <hip/hip_runtime.h>

// GridCellRouter: N=4096*4096 cells, 16 iterations of
//   accum[idx[i]] += cur[i];  cur[i] = accum[i] - cur[i]
//
// Recurrence (verified R4): c_{t+1} = S c_t + c_{t-1}, answer = c16 + c15.
// BSGS (verified R8): answer = sum_{k=0..16} alpha_k S^k r,
//   alpha = [1,8,36,84,210,252,462,330,495,220,286,78,91,14,15,1,1].
//   3 applies of S (B1,B2,B3) + 4 applies of T=S^4 (Horner, w_q fused).
//
// R11: the R3 counters showed apply_op fetches 1.07 GB/pass for a 64 MB
// compulsory gather (every line fetched 16x: srcid is a PERMUTATION, but
// reuse is scattered across buckets/XCDs so caches retain nothing).
// Replace gather-apply with a two-phase line-granular permute:
//   route: sequential NT read of ct + idxN chunk; scatter 8B records
//          (value,dst14) into per-(wg,bucket) runs via LDS cursors.
//          1024 buckets => 1024 open write lines/wg x 32 wg/XCD = 2 MB < L2
//          => L2 write-combining yields near-compact HBM writes.
//          (b3's 10x write amplification was 4096 cursors = 8 MB > L2.)
//   acc:   one wg per bucket; sequential read of records; LDS float atomic
//          acc[16384]; out = acc (+ fused w_q combination for giants).
// Records are self-describing -> b3_scatter/srcid array DELETED; build is
// counts+scans only. ALL indices masked/clamped -> no OOB possible.
// (R15 resubmit: R11-R14 never ran — GPU broker timeouts, no counters.)

#define N_CELLS (1 << 24)

#define BKT_BITS 14
#define NBKT (N_CELLS >> BKT_BITS)        // 1024 buckets
#define DPB (1 << BKT_BITS)               // 16384 dsts per bucket
#define BKT_MASK (DPB - 1)
#define IDX_MASK (N_CELLS - 1)
#define G1 256                            // wgs in b1/route
#define EDGES_PER_WG (N_CELLS / G1)       // 65536
#define BT 1024                           // threads in b1/route

typedef unsigned uv4 __attribute__((ext_vector_type(4)));
typedef float fv4 __attribute__((ext_vector_type(4)));
typedef unsigned long long u64;

__device__ __align__(16) unsigned g_T[2][NBKT * G1];       // (bucket,wg) offsets
__device__ __align__(16) unsigned g_bktcnt[2][NBKT];       // bucket totals
__device__ __align__(16) unsigned g_S[2][NBKT + 4];        // bucket starts (excl)
__device__ __align__(16) uint2 g_rec[N_CELLS];             // scratch records (val,dst14)
__device__ __align__(16) int g_idx2[N_CELLS];              // idx o idx
__device__ __align__(16) int g_idx4[N_CELLS];              // idx2 o idx2
__device__ __align__(16) float gB1[N_CELLS];               // S r
__device__ __align__(16) float gB2[N_CELLS];               // S^2 r
__device__ __align__(16) float gB3[N_CELLS];               // S^3 r
__device__ __align__(16) float gH[N_CELLS];                // Horner ping buffer

// compose: mode 0: g_idx2[i] = ext[ext[i]];  mode 1: g_idx4[i] = g_idx2[g_idx2[i]]
__global__ void compose_idx(const int* __restrict__ ext, int mode) {
    const int* __restrict__ a = mode ? g_idx2 : ext;
    int* __restrict__ o = mode ? g_idx4 : g_idx2;
    int i = (blockIdx.x * 256 + threadIdx.x) * 4;
    int4 v = *reinterpret_cast<const int4*>(a + i);
    int4 r;
    r.x = a[v.x & IDX_MASK];
    r.y = a[v.y & IDX_MASK];
    r.z = a[v.z & IDX_MASK];
    r.w = a[v.w & IDX_MASK];
    *reinterpret_cast<int4*>(o + i) = r;
}

// b1: count edges per (bucket, wg). NBKT == BT == 1024.
__global__ void __launch_bounds__(BT) b1_count(const int* __restrict__ ext, int set) {
    const int* __restrict__ idx = set ? g_idx4 : ext;
    __shared__ unsigned h[NBKT];
    int t = threadIdx.x;
    h[t] = 0u;
    __syncthreads();
    const uv4* p = reinterpret_cast<const uv4*>(idx) + (size_t)blockIdx.x * (EDGES_PER_WG / 4);
    for (int k = 0; k < EDGES_PER_WG / 4 / BT; ++k) {   // 16 iters
        uv4 v = __builtin_nontemporal_load(&p[k * BT + t]);
        atomicAdd(&h[(v.x & IDX_MASK) >> BKT_BITS], 1u);
        atomicAdd(&h[(v.y & IDX_MASK) >> BKT_BITS], 1u);
        atomicAdd(&h[(v.z & IDX_MASK) >> BKT_BITS], 1u);
        atomicAdd(&h[(v.w & IDX_MASK) >> BKT_BITS], 1u);
    }
    __syncthreads();
    g_T[set][(size_t)t * G1 + blockIdx.x] = h[t];
}

// s1: bucket totals (one wg per bucket, row of 256 is contiguous)
__global__ void s1_sums(int set) {
    __shared__ unsigned sd[256];
    int t = threadIdx.x;
    sd[t] = g_T[set][(size_t)blockIdx.x * G1 + t];
    __syncthreads();
    for (int off = 128; off > 0; off >>= 1) {
        if (t < off) sd[t] += sd[t + off];
        __syncthreads();
    }
    if (t == 0) g_bktcnt[set][blockIdx.x] = sd[0];
}

// s2: exclusive scan of g_bktcnt[1024] -> g_S. 256 threads x uint4.
__global__ void s2_scan(int set) {
    __shared__ unsigned s[256];
    int t = threadIdx.x;
    uint4 v = reinterpret_cast<const uint4*>(g_bktcnt[set])[t];
    unsigned local = v.x + v.y + v.z + v.w;
    s[t] = local;
    __syncthreads();
    for (int off = 1; off < 256; off <<= 1) {
        unsigned add = (t >= off) ? s[t - off] : 0u;
        __syncthreads();
        s[t] += add;
        __syncthreads();
    }
    unsigned run = s[t] - local;   // exclusive prefix of this thread
    uint4 o;
    o.x = run; run += v.x;
    o.y = run; run += v.y;
    o.z = run; run += v.z;
    o.w = run;
    reinterpret_cast<uint4*>(g_S[set])[t] = o;
    if (t == 0) g_S[set][NBKT] = (unsigned)N_CELLS;
}

// s3: within-bucket exclusive scan of 256 wg counts + bucket base
__global__ void s3_offsets(int set) {
    __shared__ unsigned s[256];
    int t = threadIdx.x;
    unsigned v = g_T[set][(size_t)blockIdx.x * G1 + t];
    s[t] = v;
    __syncthreads();
    for (int off = 1; off < 256; off <<= 1) {
        unsigned add = (t >= off) ? s[t - off] : 0u;
        __syncthreads();
        s[t] += add;
        __syncthreads();
    }
    g_T[set][(size_t)blockIdx.x * G1 + t] = g_S[set][blockIdx.x] + s[t] - v;
}

// pointer selector (host can't take addresses of __device__ statics)
__device__ __forceinline__ float* sel_buf(int which, const float* r, float* dout) {
    switch (which) {
        case 0: return (float*)r;
        case 1: return gB1;
        case 2: return gB2;
        case 3: return gB3;
        case 4: return gH;
        default: return dout;
    }
}

// route: phase 1 of an apply. Sequential NT reads of ct-chunk + idxN-chunk;
// scatter self-describing records (value, dst14) to per-(wg,bucket) runs.
__global__ void __launch_bounds__(BT) route_op(const float* __restrict__ rin,
                                               float* __restrict__ dout,
                                               const int* __restrict__ ext,
                                               int ct_sel, int set) {
    const int* __restrict__ idx = set ? g_idx4 : ext;
    const float* __restrict__ ct = sel_buf(ct_sel, rin, dout);
    __shared__ unsigned cur[NBKT];
    int t = threadIdx.x;
    cur[t] = g_T[set][(size_t)t * G1 + blockIdx.x];   // t < 1024 == NBKT
    __syncthreads();
    const uv4* ip = reinterpret_cast<const uv4*>(idx) + (size_t)blockIdx.x * (EDGES_PER_WG / 4);
    const fv4* cp = reinterpret_cast<const fv4*>(ct) + (size_t)blockIdx.x * (EDGES_PER_WG / 4);
    for (int k = 0; k < EDGES_PER_WG / 4 / BT; ++k) {   // 16 iters
        uv4 v = __builtin_nontemporal_load(&ip[k * BT + t]);
        fv4 c = __builtin_nontemporal_load(&cp[k * BT + t]);
        unsigned e, p;
        e = v.x & IDX_MASK; p = atomicAdd(&cur[e >> BKT_BITS], 1u) & IDX_MASK;
        g_rec[p] = make_uint2(__float_as_uint(c.x), e & BKT_MASK);
        e = v.y & IDX_MASK; p = atomicAdd(&cur[e >> BKT_BITS], 1u) & IDX_MASK;
        g_rec[p] = make_uint2(__float_as_uint(c.y), e & BKT_MASK);
        e = v.z & IDX_MASK; p = atomicAdd(&cur[e >> BKT_BITS], 1u) & IDX_MASK;
        g_rec[p] = make_uint2(__float_as_uint(c.z), e & BKT_MASK);
        e = v.w & IDX_MASK; p = atomicAdd(&cur[e >> BKT_BITS], 1u) & IDX_MASK;
        g_rec[p] = make_uint2(__float_as_uint(c.w), e & BKT_MASK);
    }
}

// acc: phase 2 of an apply. One wg per bucket; sequential record read;
// LDS float-atomic accumulate over 16384 dsts; epilogue writes
//   out[row] = acc[row] + (fuse ? a0*r + a1*B1 + a2*B2 + a3*B3 : 0)
__global__ void __launch_bounds__(512) acc_op(const float* __restrict__ rin,
                                              float* __restrict__ dout,
                                              int out_sel, int set, int fuse,
                                              float a0, float a1, float a2, float a3) {
    __shared__ float acc[DPB];   // 64 KB -> 2 wg/CU, 16 waves/CU
    int t = threadIdx.x;
    unsigned b = blockIdx.x;
    float* __restrict__ out = sel_buf(out_sel, rin, dout);
    unsigned base = g_S[set][b];
    unsigned end = g_S[set][b + 1];
    if (end > (unsigned)N_CELLS) end = (unsigned)N_CELLS;
    if (base > end) base = end;
    fv4* acc4 = reinterpret_cast<fv4*>(acc);
    fv4 z = (fv4)(0.0f);
    for (int k = 0; k < DPB / 4 / 512; ++k) acc4[k * 512 + t] = z;   // 8 iters
    __syncthreads();
    const u64* __restrict__ rec = reinterpret_cast<const u64*>(g_rec);
    unsigned e = base + t;
    for (; e + 1536 < end; e += 2048) {
        u64 q0 = __builtin_nontemporal_load(&rec[e]);
        u64 q1 = __builtin_nontemporal_load(&rec[e + 512]);
        u64 q2 = __builtin_nontemporal_load(&rec[e + 1024]);
        u64 q3 = __builtin_nontemporal_load(&rec[e + 1536]);
        atomicAdd(&acc[(unsigned)(q0 >> 32) & BKT_MASK], __uint_as_float((unsigned)q0));
        atomicAdd(&acc[(unsigned)(q1 >> 32) & BKT_MASK], __uint_as_float((unsigned)q1));
        atomicAdd(&acc[(unsigned)(q2 >> 32) & BKT_MASK], __uint_as_float((unsigned)q2));
        atomicAdd(&acc[(unsigned)(q3 >> 32) & BKT_MASK], __uint_as_float((unsigned)q3));
    }
    for (; e < end; e += 512) {
        u64 q = __builtin_nontemporal_load(&rec[e]);
        atomicAdd(&acc[(unsigned)(q >> 32) & BKT_MASK], __uint_as_float((unsigned)q));
    }
    __syncthreads();
    size_t rowbase = (size_t)b * (DPB / 4);
    fv4* out4 = reinterpret_cast<fv4*>(out) + rowbase;
    if (fuse) {
        const fv4* r4 = reinterpret_cast<const fv4*>(rin) + rowbase;
        const fv4* p1 = reinterpret_cast<const fv4*>(gB1) + rowbase;
        const fv4* p2 = reinterpret_cast<const fv4*>(gB2) + rowbase;
        const fv4* p3 = reinterpret_cast<const fv4*>(gB3) + rowbase;
        for (int k = 0; k < DPB / 4 / 512; ++k) {
            int j = k * 512 + t;
            fv4 a = acc4[j];
            fv4 x = __builtin_nontemporal_load(&r4[j]);
            fv4 y = __builtin_nontemporal_load(&p1[j]);
            fv4 u = __builtin_nontemporal_load(&p2[j]);
            fv4 w = __builtin_nontemporal_load(&p3[j]);
            a += a0 * x + a1 * y + a2 * u + a3 * w;
            __builtin_nontemporal_store(a, &out4[j]);
        }
    } else {
        for (int k = 0; k < DPB / 4 / 512; ++k) {
            int j = k * 512 + t;
            __builtin_nontemporal_store(acc4[j], &out4[j]);
        }
    }
}

extern "C" void kernel_launch(void* const* d_in, const int* in_sizes, int n_in,
                              void* d_out, int out_size, void* d_ws, size_t ws_size,
                              hipStream_t stream) {
    const int* idx = (const int*)d_in[1];
    const float* r = (const float*)d_in[0];   // read-only
    float* out = (float*)d_out;

    // ---- build S layout (set 0) ----
    b1_count<<<G1, BT, 0, stream>>>(idx, 0);
    s1_sums<<<NBKT, 256, 0, stream>>>(0);
    s2_scan<<<1, 256, 0, stream>>>(0);
    s3_offsets<<<NBKT, 256, 0, stream>>>(0);

    // ---- idx4 = idx^4; build T layout (set 1) ----
    compose_idx<<<N_CELLS / 4 / 256, 256, 0, stream>>>(idx, 0);  // g_idx2
    compose_idx<<<N_CELLS / 4 / 256, 256, 0, stream>>>(idx, 1);  // g_idx4
    b1_count<<<G1, BT, 0, stream>>>(idx, 1);
    s1_sums<<<NBKT, 256, 0, stream>>>(1);
    s2_scan<<<1, 256, 0, stream>>>(1);
    s3_offsets<<<NBKT, 256, 0, stream>>>(1);

    // ---- baby steps: B1 = S r, B2 = S B1, B3 = S B2 ----
    route_op<<<G1, BT, 0, stream>>>(r, out, idx, 0, 0);
    acc_op<<<NBKT, 512, 0, stream>>>(r, out, 1, 0, 0, 0.f, 0.f, 0.f, 0.f);
    route_op<<<G1, BT, 0, stream>>>(r, out, idx, 1, 0);
    acc_op<<<NBKT, 512, 0, stream>>>(r, out, 2, 0, 0, 0.f, 0.f, 0.f, 0.f);
    route_op<<<G1, BT, 0, stream>>>(r, out, idx, 2, 0);
    acc_op<<<NBKT, 512, 0, stream>>>(r, out, 3, 0, 0, 0.f, 0.f, 0.f, 0.f);

    // ---- giant steps: Horner over T = S^4 ----
    // alpha (k=0..16): 1,8,36,84,210,252,462,330,495,220,286,78,91,14,15,1,1
    // g3 = T r  + w3 : (91,14,15,1)      -> gH
    route_op<<<G1, BT, 0, stream>>>(r, out, idx, 0, 1);
    acc_op<<<NBKT, 512, 0, stream>>>(r, out, 4, 1, 1, 91.f, 14.f, 15.f, 1.f);
    // g2 = T g3 + w2 : (495,220,286,78)  -> d_out
    route_op<<<G1, BT, 0, stream>>>(r, out, idx, 4, 1);
    acc_op<<<NBKT, 512, 0, stream>>>(r, out, 5, 1, 1, 495.f, 220.f, 286.f, 78.f);
    // g1 = T g2 + w1 : (210,252,462,330) -> gH
    route_op<<<G1, BT, 0, stream>>>(r, out, idx, 5, 1);
    acc_op<<<NBKT, 512, 0, stream>>>(r, out, 4, 1, 1, 210.f, 252.f, 462.f, 330.f);
    // g0 = T g1 + w0 : (1,8,36,84)       -> d_out  (= answer)
    route_op<<<G1, BT, 0, stream>>>(r, out, idx, 4, 1);
    acc_op<<<NBKT, 512, 0, stream>>>(r, out, 5, 1, 1, 1.f, 8.f, 36.f, 84.f);
}